// Round 10
// baseline (159.563 us; speedup 1.0000x reference)
//
#include <hip/hip_runtime.h>
#include <stdint.h>

#define Bn 4
#define Cn 64
#define Sn 4096
#define Gn 32

typedef float v4f __attribute__((ext_vector_type(4)));
typedef short v8s __attribute__((ext_vector_type(8)));
typedef short v4s __attribute__((ext_vector_type(4)));

#define MFMA16(a,b,c) __builtin_amdgcn_mfma_f32_16x16x32_bf16((a),(b),(c),0,0,0)

__device__ __forceinline__ float bf2f(uint16_t u){
  union { uint32_t i; float f; } x; x.i = ((uint32_t)u) << 16; return x.f;
}
__device__ __forceinline__ uint16_t f2bf(float f){
  union { float f; uint32_t i; } x; x.f = f;
  uint32_t r = x.i + 0x7fffu + ((x.i >> 16) & 1u);
  return (uint16_t)(r >> 16);
}
__device__ __forceinline__ uint32_t f2bf_trunc32(float f){
  union { float f; uint32_t i; } x; x.f = f;
  return x.i >> 16;
}
__device__ __forceinline__ v8s pack8(float4 a, float4 b){
  v8s r;
  r[0]=(short)f2bf(a.x); r[1]=(short)f2bf(a.y); r[2]=(short)f2bf(a.z); r[3]=(short)f2bf(a.w);
  r[4]=(short)f2bf(b.x); r[5]=(short)f2bf(b.y); r[6]=(short)f2bf(b.z); r[7]=(short)f2bf(b.w);
  return r;
}

// ---------------- kernel 1: GroupNorm stats (mean, rstd) ----------------
__global__ __launch_bounds__(256) void gn_stats(const float* __restrict__ x,
                                                float* __restrict__ stats)
{
  const int tid = threadIdx.x;
  const float* base = x + (size_t)blockIdx.x * 8192;
  float sum = 0.f, sq = 0.f;
  #pragma unroll
  for (int i = 0; i < 8; ++i) {
    float4 v = *(const float4*)(base + ((i << 8) + tid)*4);
    sum += v.x + v.y + v.z + v.w;
    sq  += v.x*v.x + v.y*v.y + v.z*v.z + v.w*v.w;
  }
  #pragma unroll
  for (int off = 1; off < 64; off <<= 1) {
    sum += __shfl_xor(sum, off);
    sq  += __shfl_xor(sq, off);
  }
  __shared__ float red[8];
  const int w = tid >> 6;
  if ((tid & 63) == 0) { red[w] = sum; red[4+w] = sq; }
  __syncthreads();
  if (tid == 0) {
    float s = red[0]+red[1]+red[2]+red[3];
    float q = red[4]+red[5]+red[6]+red[7];
    float mean = s * (1.f/8192.f);
    float var  = q * (1.f/8192.f) - mean*mean;
    stats[blockIdx.x]       = mean;
    stats[128 + blockIdx.x] = rsqrtf(fmaxf(var, 0.f) + 1e-5f);
  }
}

// ---------------- kernel 2: normalize + QKV projection (16-row tiles) --------
// grid 1024: bx = b*256 + st, s_base = st*16. Q,K out [b][s][c]; V out [b][c][s]
__global__ __launch_bounds__(256) void gn_qkv(
    const float* __restrict__ xg, const float* __restrict__ gamma,
    const float* __restrict__ beta,
    const float* __restrict__ wq, const float* __restrict__ bq,
    const float* __restrict__ wk, const float* __restrict__ bk,
    const float* __restrict__ wv, const float* __restrict__ bv,
    const float* __restrict__ stats,
    uint16_t* __restrict__ Qg, uint16_t* __restrict__ Kg, uint16_t* __restrict__ Vg)
{
  __shared__ uint16_t Hs[16*68];   // [s][c] bf16, pad 68
  const int tid  = threadIdx.x;
  const int w    = tid >> 6;
  const int lane = tid & 63;
  const int l15  = lane & 15;
  const int quad = lane >> 4;
  const int b      = blockIdx.x >> 8;
  const int s_base = (blockIdx.x & 255) << 4;

  {
    const int c = lane;
    const int g = c >> 1;
    const float mean = stats[b*Gn + g];
    const float rstd = stats[128 + b*Gn + g];
    const float ga = gamma[c], be = beta[c];
    float4 v = *(const float4*)(xg + ((size_t)b*Cn + c)*Sn + s_base + (w << 2));
    const int r0 = w << 2;
    Hs[(r0+0)*68 + c] = f2bf((v.x - mean)*rstd*ga + be);
    Hs[(r0+1)*68 + c] = f2bf((v.y - mean)*rstd*ga + be);
    Hs[(r0+2)*68 + c] = f2bf((v.z - mean)*rstd*ga + be);
    Hs[(r0+3)*68 + c] = f2bf((v.w - mean)*rstd*ga + be);
  }
  __syncthreads();

  v8s bh0 = *(const v8s*)(Hs + l15*68 + (quad << 3));
  v8s bh1 = *(const v8s*)(Hs + l15*68 + 32 + (quad << 3));

  #pragma unroll
  for (int t = 0; t < 3; ++t) {
    const int ot   = w*3 + t;          // 0..11 across the 4 waves
    const int wsel = ot >> 2;
    const int o16  = (ot & 3) << 4;
    const float* Wsel = (wsel == 0) ? wq : (wsel == 1) ? wk : wv;
    const float* Bsel = (wsel == 0) ? bq : (wsel == 1) ? bk : bv;
    const float* Wr = Wsel + (o16 + l15)*64 + (quad << 3);
    v8s a0 = pack8(*(const float4*)(Wr),      *(const float4*)(Wr + 4));
    v8s a1 = pack8(*(const float4*)(Wr + 32), *(const float4*)(Wr + 36));
    v4f d = (v4f){0.f,0.f,0.f,0.f};
    d = MFMA16(a0, bh0, d);
    d = MFMA16(a1, bh1, d);
    const int s = s_base + l15;
    if (wsel <= 1) {
      v4s qv;
      #pragma unroll
      for (int r = 0; r < 4; ++r)
        qv[r] = (short)f2bf(d[r] + Bsel[o16 + (quad << 2) + r]);
      uint16_t* dst = (wsel == 0 ? Qg : Kg) + ((size_t)b*Sn + s)*64 + o16 + (quad << 2);
      *(v4s*)dst = qv;
    } else {
      #pragma unroll
      for (int r = 0; r < 4; ++r) {
        const int o = o16 + (quad << 2) + r;
        Vg[((size_t)b*Cn + o)*Sn + s] = f2bf(d[r] + Bsel[o]);
      }
    }
  }
}

// ---------------- kernel 3: attention, BARRIER-FREE, private per-wave LDS ----
// grid 1024: bx = ((b*64 + qt)*4 + split); 64 q/block, 1024 keys/split, 16 tiles.
// 4 waves = (qh, kh): wave owns 32 q x 32 keys of each 64-key tile, and stages
// its OWN K-half/V-half into private frag-major LDS (no __syncthreads at all).
// S^T = K Q^T (A=K LDS, B=Q regs); P goes C-layout -> A-layout via ds_bpermute
// shuffles (no LDS round-trip). Partials per (split,kh) merged in proj_res.
__global__ __launch_bounds__(256, 4) void attn_split(
    const uint16_t* __restrict__ Qg, const uint16_t* __restrict__ Kg,
    const uint16_t* __restrict__ Vg,
    uint16_t* __restrict__ Opart, float* __restrict__ lpart)
{
  __shared__ uint16_t KT[4][2048];   // per-wave: 4 slots (T,kc) x 512 elems
  __shared__ uint16_t VT[4][2048];   // per-wave: 4 slots (n)    x 512 elems

  const int tid  = threadIdx.x;
  const int w    = tid >> 6;
  const int lane = tid & 63;
  const int l15  = lane & 15;
  const int quad = lane >> 4;
  const int qh   = w & 1;            // query half (32 q)
  const int kh   = w >> 1;           // key half (32 of each 64-key tile)
  const int bx    = blockIdx.x;
  const int split = bx & 3;
  const int qt    = (bx >> 2) & 63;
  const int b     = bx >> 8;
  const int i_base = qt << 6;
  const int j0     = split << 10;

  const uint16_t* Qb = Qg + ((size_t)b*Sn + i_base)*64;
  const uint16_t* Kb = Kg + (size_t)b*Sn*64;
  const uint16_t* Vb = Vg + (size_t)b*Cn*Sn;

  // Q B-fragments in registers: q = qh*32 + t*16 + l15, k-chunk kc
  v8s qf[2][2];
  #pragma unroll
  for (int t = 0; t < 2; ++t) {
    const uint16_t* qr = Qb + (size_t)((qh << 5) + (t << 4) + l15)*64;
    qf[t][0] = *(const v8s*)(qr + (quad << 3));
    qf[t][1] = *(const v8s*)(qr + 32 + (quad << 3));
  }

  uint16_t* KTw = KT[w];
  uint16_t* VTw = VT[w];
  const int hi8 = quad << 3;         // within-row 8-elem chunk

  // stage tile 0 (private; same-wave ordering only)
  #pragma unroll
  for (int sl = 0; sl < 4; ++sl) {
    // K slot(T=sl>>1, kc=sl&1): K[j0 + kh*32 + T*16 + l15][kc*32 + quad*8 ..]
    v8s kv = *(const v8s*)(Kb + (size_t)(j0 + (kh << 5) + ((sl >> 1) << 4) + l15)*64
                               + ((sl & 1) << 5) + hi8);
    *(v8s*)(KTw + (sl << 9) + (lane << 3)) = kv;
    // V slot(n=sl): V[c = n*16 + l15][j0 + kh*32 + quad*8 ..]
    v8s vv = *(const v8s*)(Vb + (size_t)((sl << 4) + l15)*Sn + j0 + (kh << 5) + hi8);
    *(v8s*)(VTw + (sl << 9) + (lane << 3)) = vv;
  }

  float lsum[2] = {0.f, 0.f};
  v4f o_acc[2][4];
  #pragma unroll
  for (int t = 0; t < 2; ++t)
    #pragma unroll
    for (int n = 0; n < 4; ++n) o_acc[t][n] = (v4f){0.f,0.f,0.f,0.f};

  const float SC = 0.18033688011112042f;   // (1/sqrt(64)) * log2(e)
  const int slbase = l15 + ((quad & 1) << 5);  // bpermute src lane base
  const int tsel   = quad >> 1;                // T select for exchange

  for (int kt = 0; kt < 16; ++kt) {
    // prefetch next tile into registers (no barrier needed; private LDS)
    v8s kp[4], vp[4];
    if (kt < 15) {
      const int jn = j0 + ((kt + 1) << 6);
      #pragma unroll
      for (int sl = 0; sl < 4; ++sl) {
        kp[sl] = *(const v8s*)(Kb + (size_t)(jn + (kh << 5) + ((sl >> 1) << 4) + l15)*64
                                   + ((sl & 1) << 5) + hi8);
        vp[sl] = *(const v8s*)(Vb + (size_t)((sl << 4) + l15)*Sn + jn + (kh << 5) + hi8);
      }
    }

    // S^T = K Q^T : A=K slots, B=Q regs.  st[T][t][r] = S^T[T*16+quad*4+r][t*16+l15]
    v4f st[2][2];
    #pragma unroll
    for (int T = 0; T < 2; ++T) {
      v8s ka0 = *(const v8s*)(KTw + (((T << 1) + 0) << 9) + (lane << 3));
      v8s ka1 = *(const v8s*)(KTw + (((T << 1) + 1) << 9) + (lane << 3));
      #pragma unroll
      for (int t = 0; t < 2; ++t) {
        v4f acc = (v4f){0.f,0.f,0.f,0.f};
        acc = MFMA16(ka0, qf[t][0], acc);
        acc = MFMA16(ka1, qf[t][1], acc);
        st[T][t] = acc;
      }
    }

    // p = 2^(s*SC), pack to bf16 dword pairs pk[T][t][d]
    uint32_t pk[2][2][2];
    #pragma unroll
    for (int T = 0; T < 2; ++T)
      #pragma unroll
      for (int t = 0; t < 2; ++t)
        #pragma unroll
        for (int d = 0; d < 2; ++d) {
          const float p0 = __builtin_amdgcn_exp2f(st[T][t][2*d]*SC);
          const float p1 = __builtin_amdgcn_exp2f(st[T][t][2*d+1]*SC);
          lsum[t] += p0 + p1;
          pk[T][t][d] = f2bf_trunc32(p0) | (f2bf_trunc32(p1) << 16);
        }

    // exchange: C-layout -> A-layout for PV, via ds_bpermute + select.
    // target lane needs P[q=t*16+l15][j=quad*8+2*i2 + {0,1}] =
    //   src lane (l15 + 16*((quad&1)*2 + (i2>>1))), subtile T=quad>>1, dword i2&1
    v8s ap[2];
    #pragma unroll
    for (int t = 0; t < 2; ++t) {
      union { int i[4]; v8s v; } u;
      #pragma unroll
      for (int i2 = 0; i2 < 4; ++i2) {
        const int sl_ = slbase + ((i2 >> 1) << 4);
        const int v0 = __shfl((int)pk[0][t][i2 & 1], sl_, 64);
        const int v1 = __shfl((int)pk[1][t][i2 & 1], sl_, 64);
        u.i[i2] = tsel ? v1 : v0;
      }
      ap[t] = u.v;
    }

    // O += P V : B=V slots (n), k = this wave's 32 keys
    #pragma unroll
    for (int n = 0; n < 4; ++n) {
      v8s vb = *(const v8s*)(VTw + (n << 9) + (lane << 3));
      #pragma unroll
      for (int t = 0; t < 2; ++t)
        o_acc[t][n] = MFMA16(ap[t], vb, o_acc[t][n]);
    }

    // write back prefetched tile (program order guarantees reads-before-writes)
    if (kt < 15) {
      #pragma unroll
      for (int sl = 0; sl < 4; ++sl) {
        *(v8s*)(KTw + (sl << 9) + (lane << 3)) = kp[sl];
        *(v8s*)(VTw + (sl << 9) + (lane << 3)) = vp[sl];
      }
    }
  }

  // reduce l across quads (lanes sharing l15)
  #pragma unroll
  for (int t = 0; t < 2; ++t) {
    lsum[t] += __shfl_xor(lsum[t], 16);
    lsum[t] += __shfl_xor(lsum[t], 32);
  }

  // write this (split, kh) partial: O [64 q][64 c] bf16, l [64 q] f32
  uint16_t* Ob = Opart + ((size_t)bx*2 + kh)*4096;
  float*    lp = lpart + ((size_t)bx*2 + kh)*64;
  #pragma unroll
  for (int t = 0; t < 2; ++t) {
    #pragma unroll
    for (int n = 0; n < 4; ++n)
      #pragma unroll
      for (int r = 0; r < 4; ++r)
        Ob[((qh << 5) + (t << 4) + (quad << 2) + r)*64 + (n << 4) + l15] = f2bf(o_acc[t][n][r]);
    if (quad == 0) lp[(qh << 5) + (t << 4) + l15] = lsum[t];
  }
}

// ---------------- kernel 4: merge 8 partials + projection + residual ---------
// grid 1024: bx = b*256 + st; s rows [st*16, +16). out[b][c][s] = x + Wp@A + bp
__global__ __launch_bounds__(256) void proj_res(
    const uint16_t* __restrict__ Opart, const float* __restrict__ lpart,
    const float* __restrict__ wp, const float* __restrict__ bp,
    const float* __restrict__ xg, float* __restrict__ out)
{
  __shared__ uint16_t As[16*68];   // merged attention subtile [s][c]
  const int tid  = threadIdx.x;
  const int w    = tid >> 6;
  const int lane = tid & 63;
  const int l15  = lane & 15;
  const int quad = lane >> 4;
  const int b      = blockIdx.x >> 8;
  const int st     = blockIdx.x & 255;
  const int qt     = st >> 2;
  const int sub    = st & 3;
  const int s_base = st << 4;

  const uint16_t* po = Opart + (size_t)((b*64 + qt)*8)*4096 + (sub << 4)*64;
  const float*    pl = lpart + ((b*64 + qt)*8)*64 + (sub << 4);

  { // merge 8 partials: thread t -> 4 elems, row = t>>4, col = (t&15)*4
    const int e = tid << 2, row = tid >> 4, col = (tid & 15) << 2;
    float lsum = 0.f;
    #pragma unroll
    for (int sp = 0; sp < 8; ++sp) lsum += pl[sp*64 + row];
    const float linv = 1.f / lsum;
    float acc[4] = {0.f,0.f,0.f,0.f};
    #pragma unroll
    for (int sp = 0; sp < 8; ++sp) {
      v4s o = *(const v4s*)(po + sp*4096 + e);
      #pragma unroll
      for (int j = 0; j < 4; ++j) acc[j] += bf2f((uint16_t)o[j]);
    }
    v4s a;
    #pragma unroll
    for (int j = 0; j < 4; ++j) a[j] = (short)f2bf(acc[j]*linv);
    *(v4s*)(As + row*68 + col) = a;
  }
  __syncthreads();

  v8s ba0 = *(const v8s*)(As + l15*68 + (quad << 3));
  v8s ba1 = *(const v8s*)(As + l15*68 + 32 + (quad << 3));

  // wave w computes output channels [w*16, +16)
  const float* Wr = wp + ((w << 4) + l15)*64 + (quad << 3);
  v8s a0 = pack8(*(const float4*)(Wr),      *(const float4*)(Wr + 4));
  v8s a1 = pack8(*(const float4*)(Wr + 32), *(const float4*)(Wr + 36));
  v4f d = (v4f){0.f,0.f,0.f,0.f};
  d = MFMA16(a0, ba0, d);
  d = MFMA16(a1, ba1, d);
  const int s = s_base + l15;
  #pragma unroll
  for (int r = 0; r < 4; ++r) {
    const int o = (w << 4) + (quad << 2) + r;
    const size_t idx = ((size_t)b*Cn + o)*Sn + s;
    out[idx] = d[r] + bp[o] + xg[idx];
  }
}

extern "C" void kernel_launch(void* const* d_in, const int* in_sizes, int n_in,
                              void* d_out, int out_size, void* d_ws, size_t ws_size,
                              hipStream_t stream)
{
  const float* x     = (const float*)d_in[0];
  const float* gamma = (const float*)d_in[1];
  const float* beta  = (const float*)d_in[2];
  const float* wq    = (const float*)d_in[3];
  const float* bq    = (const float*)d_in[4];
  const float* wk    = (const float*)d_in[5];
  const float* bk    = (const float*)d_in[6];
  const float* wv    = (const float*)d_in[7];
  const float* bv    = (const float*)d_in[8];
  const float* wp    = (const float*)d_in[9];
  const float* bp    = (const float*)d_in[10];

  float*    stats = (float*)d_ws;                        // 256 floats
  uint16_t* Qg    = (uint16_t*)d_ws + 1024;              // [B][S][C] bf16 (2 MiB)
  uint16_t* Kg    = Qg + (size_t)Bn*Sn*Cn;               // [B][S][C]
  uint16_t* Vg    = Kg + (size_t)Bn*Sn*Cn;               // [B][C][S]
  uint16_t* Opart = Vg + (size_t)Bn*Sn*Cn;               // 2048 x 64 x 64 bf16 (16 MiB)
  float*    lpart = (float*)(Opart + (size_t)2048*4096); // 2048 x 64 f32 (512 KiB)
  float*    outp  = (float*)d_out;

  gn_stats  <<<128, 256, 0, stream>>>(x, stats);
  gn_qkv    <<<1024, 256, 0, stream>>>(x, gamma, beta, wq, bq, wk, bk, wv, bv,
                                       stats, Qg, Kg, Vg);
  attn_split<<<1024, 256, 0, stream>>>(Qg, Kg, Vg, Opart, lpart);
  proj_res  <<<1024, 256, 0, stream>>>(Opart, lpart, wp, bp, x, outp);
}